// Round 9
// baseline (320.558 us; speedup 1.0000x reference)
//
#include <hip/hip_runtime.h>
#include <limits.h>

#define BLOCK 128
#define CHUNK 3

typedef float v2f __attribute__((ext_vector_type(2)));
typedef float f4  __attribute__((ext_vector_type(4)));

// Constant-address-space weight access: uniform address + AS4 => s_load
// (SGPR broadcast, scalar cache). Verified R4/R6: weight stream rides the
// scalar pipe. CHUNK ladder: 2 -> 58.5us (VGPR 52); 4 refuted twice (R3
// spills; R7 VGPR=132 -> tier collapse + allocator bloat). CHUNK=3 is the
// untested midpoint: per-wave fixed costs (weight stream ~200 s_load
// clusters, scan, prologue) amortized over 192 atoms, VGPR est ~80 < 128.
#define AS4 __attribute__((address_space(4)))
typedef AS4 const float cf;
typedef AS4 const f4    cf4;
typedef AS4 const v2f   cv2f;

__device__ __forceinline__ v2f pk_fma(v2f a, v2f b, v2f c) {
    return __builtin_elementwise_fma(a, b, c);
}
__device__ __forceinline__ float leaky_(float x){ return x >= 0.f ? x : 0.01f*x; }

// Packed weight-table layout (floats) in GLOBAL memory, read via AS4:
#define L_W2AI   0      // 16*20: k-pair interleaved {w2a[2kp][j],w2a[2kp+1][j]} j<9, pad 2
#define L_W2BT   320    // 32*16: w2bT[k][m] = w2b[m*32+k]
#define L_W2CT   832    // 16*8 : w2cT[m][p] = w2c[p*16+m], pad p<8
#define L_B2B    960    // 16
#define L_B2C    976    // 8 (pad)
#define L_W013   984    // 3 mats x 3 rows x4: (w,w,w,b) for w0,w1,w1n
#define WTAB_SZ  1024

// ---------------- Kernel A: per-structure precompute + weight packing ------
__global__ void prep_kernel(const float* __restrict__ cell,
                            const float* __restrict__ w2a,
                            const float* __restrict__ b2a,
                            const float* __restrict__ w2b,
                            const float* __restrict__ w2c,
                            const float* __restrict__ w0, const float* __restrict__ b0,
                            const float* __restrict__ w1, const float* __restrict__ b1,
                            const float* __restrict__ w1n, const float* __restrict__ b1n,
                            const float* __restrict__ b2b, const float* __restrict__ b2c,
                            float* __restrict__ ci_out,
                            float* __restrict__ cc_out,
                            float* __restrict__ wtab,
                            float* __restrict__ out_zero,
                            int S)
{
    __shared__ float sw[2880];          // all of w2a [32][90]
    int tid = threadIdx.x;
    int gid = blockIdx.x * blockDim.x + tid;

    #pragma unroll
    for (int t = 0; t < 3; t++) {
        int idx = tid + t*256;
        if (idx < 720) ((float4*)sw)[idx] = ((const float4*)w2a)[idx];
    }

    if (gid < S * 6) out_zero[gid] = 0.f;

    // ---- wtab packing (few threads; scattered loads negligible) ----
    if (gid < 320) {
        int kp = gid / 20, idx = gid % 20;
        int j = idx >> 1, h = idx & 1;
        wtab[L_W2AI + gid] = (idx < 18) ? w2a[(2*kp + h)*90 + j] : 0.f;
    } else if (gid < 832) {
        int t = gid - 320; int k = t >> 4, m = t & 15;
        wtab[gid] = w2b[m*32 + k];
    } else if (gid < 960) {
        int t = gid - 832; int m = t >> 3, p = t & 7;
        wtab[gid] = (p < 6) ? w2c[p*16 + m] : 0.f;
    } else if (gid < 976) {
        wtab[gid] = b2b[gid - 960];
    } else if (gid < 984) {
        int t = gid - 976; wtab[gid] = (t < 6) ? b2c[t] : 0.f;
    } else if (gid < 1024) {
        int t = gid - 984;
        if (t < 36) {
            int mat = t / 12, rr = t % 12, r = rr >> 2, c = rr & 3;
            const float* W = (mat == 0) ? w0 : (mat == 1) ? w1 : w1n;
            const float* B = (mat == 0) ? b0 : (mat == 1) ? b1 : b1n;
            wtab[gid] = (c < 3) ? W[r*3 + c] : B[r];
        } else wtab[gid] = 0.f;
    }

    __syncthreads();

    int s = gid >> 5;
    if (s >= S) return;
    int k = gid & 31;

    float cr[9];
    #pragma unroll
    for (int j = 0; j < 9; j++) cr[j] = cell[s*9 + j];

    if (k == 0) {
        float a=cr[0],b=cr[1],c=cr[2],d=cr[3],e=cr[4],f=cr[5],g=cr[6],h=cr[7],i=cr[8];
        float A = e*i - f*h;
        float B = f*g - d*i;
        float C = d*h - e*g;
        float det = a*A + b*B + c*C;
        float r = 1.0f / det;
        float* o = ci_out + s*12;
        o[0] = A*r;         o[1] = (c*h - b*i)*r; o[2] = (b*f - c*e)*r;
        o[3] = B*r;         o[4] = (a*i - c*g)*r; o[5] = (c*d - a*f)*r;
        o[6] = C*r;         o[7] = (b*g - a*h)*r; o[8] = (a*e - b*d)*r;
        o[9] = 0.f; o[10] = 0.f; o[11] = 0.f;
    }

    float acc = b2a[k];
    const float* wr = sw + k*90 + 9;     // LDS
    #pragma unroll
    for (int j1 = 0; j1 < 9; j1++) {
        float c1 = cr[j1];
        #pragma unroll
        for (int j2 = 0; j2 < 9; j2++)
            acc = fmaf(c1 * cr[j2], wr[j1*9 + j2], acc);
    }
    cc_out[s*32 + k] = acc;
}

// ---------------- Kernel B: per-atom MLP + segment sum ---------------------
// R8 body (SMEM weights, shufflevector splats, 2-deep cc pipeline, no LDS,
// no barriers, direct-atomic tails) at CHUNK=3.
__global__ __launch_bounds__(BLOCK)
void main_kernel(const float* __restrict__ atom_prop,
                 const float* __restrict__ pos,
                 const int*   __restrict__ batch,
                 const float* __restrict__ ci_ws,
                 const float* __restrict__ cc_ws,
                 const float* __restrict__ wtab,
                 float* __restrict__ out,
                 int N, int S, int ntiles)
{
    int tid = threadIdx.x;
    int tile = blockIdx.x;
    if (tile >= ntiles) return;

    // AS4 view of the weight table (cast via integer to sidestep
    // addrspace-conversion rules; the memory is written only by prep_kernel).
    cf* wt = (cf*)(unsigned long long)wtab;

    long long blk_base = (long long)tile * (BLOCK * CHUNK);
    long long base = blk_base + (long long)tid * CHUNK;
    bool any = (base < N);

    int   sv[CHUNK];
    float PX[CHUNK], PY[CHUNK], PZ[CHUNK];
    float AX[CHUNK], AY[CHUNK], AZ[CHUNK];

    if (any && base + CHUNK <= N) {
        // contiguous scalar loads; the load-store vectorizer merges
        // 4B-aligned fp32/int runs into dwordx4/x3 (stride-3 base breaks
        // 8/16B alignment, so no explicit vector casts here).
        const int* bb = batch + base;
        #pragma unroll
        for (int t = 0; t < CHUNK; t++) sv[t] = bb[t];
        const float* pp = pos + 3*base;
        const float* ap = atom_prop + 3*base;
        #pragma unroll
        for (int t = 0; t < CHUNK; t++) {
            PX[t] = pp[3*t]; PY[t] = pp[3*t+1]; PZ[t] = pp[3*t+2];
            AX[t] = ap[3*t]; AY[t] = ap[3*t+1]; AZ[t] = ap[3*t+2];
        }
    } else {
        #pragma unroll
        for (int t = 0; t < CHUNK; t++) {
            long long i = base + t;
            bool ok = any && (i < N);
            sv[t] = ok ? batch[i] : -1;
            PX[t] = ok ? pos[3*i]   : 0.f;
            PY[t] = ok ? pos[3*i+1] : 0.f;
            PZ[t] = ok ? pos[3*i+2] : 0.f;
            AX[t] = ok ? atom_prop[3*i]   : 0.f;
            AY[t] = ok ? atom_prop[3*i+1] : 0.f;
            AZ[t] = ok ? atom_prop[3*i+2] : 0.f;
        }
    }

    // issue cc prefetch early, 2 blocks deep (covers ~2x L2 latency in kb loop)
    const float* ccp[CHUNK];
    #pragma unroll
    for (int t = 0; t < CHUNK; t++) {
        int s = sv[t] < 0 ? 0 : sv[t];
        ccp[t] = cc_ws + (size_t)s*32;
    }
    f4 c4n[CHUNK], c4nn[CHUNK];
    #pragma unroll
    for (int t = 0; t < CHUNK; t++) c4n[t]  = *(const f4*)(ccp[t]);
    #pragma unroll
    for (int t = 0; t < CHUNK; t++) c4nn[t] = *(const f4*)(ccp[t] + 4);

    // ---- phase 1: h per atom (splat pairs); w0/w1/w1n rows via s_load ----
    v2f h2[CHUNK][9];
    {
        cf4* q0 = (cf4*)(wt + L_W013);
        cf4* q1 = (cf4*)(wt + L_W013 + 12);
        cf4* q2 = (cf4*)(wt + L_W013 + 24);
        int   cur_s = -1;
        float ci[9];
        #pragma unroll
        for (int t = 0; t < CHUNK; t++) {
            int s = sv[t];
            if (s < 0) {
                #pragma unroll
                for (int j = 0; j < 9; j++) h2[t][j] = 0.f;
                continue;
            }
            if (s != cur_s) {
                cur_s = s;
                const f4* cip = (const f4*)(ci_ws + (size_t)s*12);
                f4 c0 = cip[0], c1 = cip[1], c2 = cip[2];
                ci[0]=c0.x; ci[1]=c0.y; ci[2]=c0.z; ci[3]=c0.w;
                ci[4]=c1.x; ci[5]=c1.y; ci[6]=c1.z; ci[7]=c1.w;
                ci[8]=c2.x;
            }
            float px = PX[t], py = PY[t], pz = PZ[t];
            float ax = AX[t], ay = AY[t], az = AZ[t];

            float f0 = fmaf(px, ci[0], fmaf(py, ci[3], pz*ci[6]));
            float f1 = fmaf(px, ci[1], fmaf(py, ci[4], pz*ci[7]));
            float f2 = fmaf(px, ci[2], fmaf(py, ci[5], pz*ci[8]));
            float t0 = f0 - floorf(f0) - 0.5f;
            float t1 = f1 - floorf(f1) - 0.5f;
            float t2 = f2 - floorf(f2) - 0.5f;

            h2[t][0].x = h2[t][0].y = ax;
            h2[t][1].x = h2[t][1].y = ay;
            h2[t][2].x = h2[t][2].y = az;
            #pragma unroll
            for (int r = 0; r < 3; r++) {
                f4 a0 = q0[r], a1 = q1[r], a2 = q2[r];
                float ap3 = leaky_(fmaf(ax, a0.x, fmaf(ay, a0.y, fmaf(az, a0.z, a0.w))));
                float d1  = fmaf(t0, a1.x, fmaf(t1, a1.y, fmaf(t2, a1.z, a1.w)));
                float d2  = a2.w - fmaf(t0, a2.x, fmaf(t1, a2.y, t2*a2.z));
                float v1 = fmaxf(d1, 0.f) * ap3;
                float v2 = fmaxf(d2, 0.f) * ap3;
                h2[t][3+r].x = h2[t][3+r].y = v1;
                h2[t][6+r].x = h2[t][6+r].y = v2;
            }
        }
    }

    // ---- phase 2: fused L1+relu+L2; k-pair packed; SMEM weights;
    //      cc loads software-pipelined 2 blocks deep; weights read once
    //      per k-pair and reused across all CHUNK atoms ----
    v2f vv[CHUNK][8];
    {
        cv2f* b2b2 = (cv2f*)(wt + L_B2B);
        #pragma unroll
        for (int t = 0; t < CHUNK; t++)
            #pragma unroll
            for (int m2 = 0; m2 < 8; m2++) vv[t][m2] = b2b2[m2];
    }

    #pragma unroll
    for (int kb = 0; kb < 8; kb++) {
        f4 c4[CHUNK];
        #pragma unroll
        for (int t = 0; t < CHUNK; t++) c4[t] = c4n[t];
        #pragma unroll
        for (int t = 0; t < CHUNK; t++) c4n[t] = c4nn[t];
        if (kb < 6) {
            #pragma unroll
            for (int t = 0; t < CHUNK; t++) c4nn[t] = *(const f4*)(ccp[t] + (kb+2)*4);
        }

        #pragma unroll
        for (int h = 0; h < 2; h++) {
            int kp = 2*kb + h;
            cv2f* wI  = (cv2f*)(wt + L_W2AI + kp*20);       // uniform -> s_load pairs
            cv2f* wb0 = (cv2f*)(wt + L_W2BT + (2*kp)*16);
            cv2f* wb1 = (cv2f*)(wt + L_W2BT + (2*kp+1)*16);
            #pragma unroll
            for (int t = 0; t < CHUNK; t++) {
                v2f u2;
                u2.x = h ? c4[t].z : c4[t].x;
                u2.y = h ? c4[t].w : c4[t].y;
                #pragma unroll
                for (int j = 0; j < 9; j++) u2 = pk_fma(h2[t][j], wI[j], u2);
                v2f zero = 0.f;
                u2 = __builtin_elementwise_max(u2, zero);
                v2f ux = __builtin_shufflevector(u2, u2, 0, 0);
                v2f uy = __builtin_shufflevector(u2, u2, 1, 1);
                #pragma unroll
                for (int m2 = 0; m2 < 8; m2++) {
                    vv[t][m2] = pk_fma(ux, wb0[m2], vv[t][m2]);
                    vv[t][m2] = pk_fma(uy, wb1[m2], vv[t][m2]);
                }
            }
        }
    }

    // ---- epilogue: leaky, L3 (16->6) ----
    {
        v2f zero = 0.f, small = 0.01f;
        #pragma unroll
        for (int t = 0; t < CHUNK; t++)
            #pragma unroll
            for (int m2 = 0; m2 < 8; m2++) {
                v2f mx = __builtin_elementwise_max(vv[t][m2], zero);
                v2f mn = __builtin_elementwise_min(vv[t][m2], zero);
                vv[t][m2] = pk_fma(mn, small, mx);
            }
    }

    v2f oo[CHUNK][3];
    {
        cv2f* b2c2 = (cv2f*)(wt + L_B2C);
        #pragma unroll
        for (int t = 0; t < CHUNK; t++)
            #pragma unroll
            for (int p2 = 0; p2 < 3; p2++) oo[t][p2] = b2c2[p2];
    }
    #pragma unroll
    for (int m2 = 0; m2 < 8; m2++) {
        cv2f* wc0 = (cv2f*)(wt + L_W2CT + (2*m2)*8);   // uniform
        cv2f* wc1 = (cv2f*)(wt + L_W2CT + (2*m2+1)*8);
        #pragma unroll
        for (int t = 0; t < CHUNK; t++) {
            v2f vm = vv[t][m2];
            v2f a = __builtin_shufflevector(vm, vm, 0, 0);
            v2f b = __builtin_shufflevector(vm, vm, 1, 1);
            #pragma unroll
            for (int p2 = 0; p2 < 3; p2++)
                oo[t][p2] = pk_fma(a, wc0[p2], pk_fma(b, wc1[p2], oo[t][p2]));
        }
    }

    // ---- per-lane final: sequential merge over the CHUNK sorted keys;
    //      intra-thread boundary tails -> direct global atomics ----
    const int SENT = INT_MAX;
    int fs = SENT;
    float fin[6] = {0.f, 0.f, 0.f, 0.f, 0.f, 0.f};
    #pragma unroll
    for (int t = 0; t < CHUNK; t++) {
        int s = sv[t];
        if (s < 0) continue;
        float o6[6] = {oo[t][0].x, oo[t][0].y, oo[t][1].x,
                       oo[t][1].y, oo[t][2].x, oo[t][2].y};
        if (s == fs) {
            #pragma unroll
            for (int p = 0; p < 6; p++) fin[p] += o6[p];
        } else {
            if (fs != SENT) {
                #pragma unroll
                for (int p = 0; p < 6; p++) atomicAdd(out + (size_t)fs*6 + p, fin[p]);
            }
            fs = s;
            #pragma unroll
            for (int p = 0; p < 6; p++) fin[p] = o6[p];
        }
    }

    // ---- segmented inclusive scan across the wave (keys sorted) ----
    int lane = tid & 63;
    #pragma unroll
    for (int d = 1; d < 64; d <<= 1) {
        int ks = __shfl_up(fs, d);
        bool pred = (lane >= d) && (ks == fs);
        #pragma unroll
        for (int p = 0; p < 6; p++) {
            float vp = __shfl_up(fin[p], d);
            fin[p] += pred ? vp : 0.f;
        }
    }
    {
        int sn = __shfl_down(fs, 1);
        bool tail = (lane == 63) || (sn != fs);
        if (tail && fs != SENT) {
            #pragma unroll
            for (int p = 0; p < 6; p++) atomicAdd(out + (size_t)fs*6 + p, fin[p]);
        }
    }
}

extern "C" void kernel_launch(void* const* d_in, const int* in_sizes, int n_in,
                              void* d_out, int out_size, void* d_ws, size_t ws_size,
                              hipStream_t stream)
{
    const float* atom_prop = (const float*)d_in[0];
    const float* pos       = (const float*)d_in[1];
    const float* cell      = (const float*)d_in[2];
    const int*   batch     = (const int*)  d_in[3];
    const float* w0  = (const float*)d_in[4];
    const float* b0  = (const float*)d_in[5];
    const float* w1  = (const float*)d_in[6];
    const float* b1  = (const float*)d_in[7];
    const float* w1n = (const float*)d_in[8];
    const float* b1n = (const float*)d_in[9];
    const float* w2a = (const float*)d_in[10];
    const float* b2a = (const float*)d_in[11];
    const float* w2b = (const float*)d_in[12];
    const float* b2b = (const float*)d_in[13];
    const float* w2c = (const float*)d_in[14];
    const float* b2c = (const float*)d_in[15];

    int N = in_sizes[3];          // batch has one entry per atom
    int S = in_sizes[2] / 9;      // cell is [S,3,3]

    float* out   = (float*)d_out;
    float* ci_ws = (float*)d_ws;                 // [S*12]
    float* cc_ws = ci_ws + (size_t)S*12;         // [S*32]
    float* wtab  = cc_ws + (size_t)S*32;         // [1024]

    int prep_threads = S * 32;
    prep_kernel<<<(prep_threads + 255)/256, 256, 0, stream>>>(
        cell, w2a, b2a, w2b, w2c, w0, b0, w1, b1, w1n, b1n, b2b, b2c,
        ci_ws, cc_ws, wtab, out, S);

    int tile_atoms = BLOCK * CHUNK;
    int ntiles = (N + tile_atoms - 1) / tile_atoms;
    main_kernel<<<ntiles, BLOCK, 0, stream>>>(atom_prop, pos, batch,
                                              ci_ws, cc_ws, wtab, out, N, S, ntiles);
}

// Round 10
// 164.626 us; speedup vs baseline: 1.9472x; 1.9472x over previous
//
#include <hip/hip_runtime.h>
#include <limits.h>

#define BLOCK 128
#define CHUNK 2

typedef float v2f __attribute__((ext_vector_type(2)));
typedef float f4  __attribute__((ext_vector_type(4)));

// Constant-address-space weight access: uniform address + AS4 => s_load
// (SGPR broadcast, scalar cache). Verified R4/R6. CHUNK axis closed: 2 is
// optimal (3 and 4 refuted: VGPR tier collapse / allocator bloat).
// R10: weight stream SPLIT across pipes — w2bT (512 floats) rides the idle
// DS pipe from LDS (b128 broadcast reads), wI/w2cT/biases stay on SMEM.
// Halving the s_load stream lets ~2-3 k-pairs fit the ~102-SGPR prefetch
// window (stalls hidden); DS adds ~1536 cyc/wave which overlaps VALU
// across waves (m114: concurrent pipes => time ~= max, not sum).
#define AS4 __attribute__((address_space(4)))
typedef AS4 const float cf;
typedef AS4 const f4    cf4;
typedef AS4 const v2f   cv2f;

__device__ __forceinline__ v2f pk_fma(v2f a, v2f b, v2f c) {
    return __builtin_elementwise_fma(a, b, c);
}
__device__ __forceinline__ float leaky_(float x){ return x >= 0.f ? x : 0.01f*x; }

// Packed weight-table layout (floats) in GLOBAL memory:
#define L_W2AI   0      // 16*20: k-pair interleaved {w2a[2kp][j],w2a[2kp+1][j]} j<9, pad 2
#define L_W2BT   320    // 32*16: w2bT[k][m] = w2b[m*32+k]   (staged to LDS by main)
#define L_W2CT   832    // 16*8 : w2cT[m][p] = w2c[p*16+m], pad p<8
#define L_B2B    960    // 16
#define L_B2C    976    // 8 (pad)
#define L_W013   984    // 3 mats x 3 rows x4: (w,w,w,b) for w0,w1,w1n
#define WTAB_SZ  1024

// ---------------- Kernel A: per-structure precompute + weight packing ------
__global__ void prep_kernel(const float* __restrict__ cell,
                            const float* __restrict__ w2a,
                            const float* __restrict__ b2a,
                            const float* __restrict__ w2b,
                            const float* __restrict__ w2c,
                            const float* __restrict__ w0, const float* __restrict__ b0,
                            const float* __restrict__ w1, const float* __restrict__ b1,
                            const float* __restrict__ w1n, const float* __restrict__ b1n,
                            const float* __restrict__ b2b, const float* __restrict__ b2c,
                            float* __restrict__ ci_out,
                            float* __restrict__ cc_out,
                            float* __restrict__ wtab,
                            float* __restrict__ out_zero,
                            int S)
{
    __shared__ float sw[2880];          // all of w2a [32][90]
    int tid = threadIdx.x;
    int gid = blockIdx.x * blockDim.x + tid;

    #pragma unroll
    for (int t = 0; t < 3; t++) {
        int idx = tid + t*256;
        if (idx < 720) ((float4*)sw)[idx] = ((const float4*)w2a)[idx];
    }

    if (gid < S * 6) out_zero[gid] = 0.f;

    // ---- wtab packing (few threads; scattered loads negligible) ----
    if (gid < 320) {
        int kp = gid / 20, idx = gid % 20;
        int j = idx >> 1, h = idx & 1;
        wtab[L_W2AI + gid] = (idx < 18) ? w2a[(2*kp + h)*90 + j] : 0.f;
    } else if (gid < 832) {
        int t = gid - 320; int k = t >> 4, m = t & 15;
        wtab[gid] = w2b[m*32 + k];
    } else if (gid < 960) {
        int t = gid - 832; int m = t >> 3, p = t & 7;
        wtab[gid] = (p < 6) ? w2c[p*16 + m] : 0.f;
    } else if (gid < 976) {
        wtab[gid] = b2b[gid - 960];
    } else if (gid < 984) {
        int t = gid - 976; wtab[gid] = (t < 6) ? b2c[t] : 0.f;
    } else if (gid < 1024) {
        int t = gid - 984;
        if (t < 36) {
            int mat = t / 12, rr = t % 12, r = rr >> 2, c = rr & 3;
            const float* W = (mat == 0) ? w0 : (mat == 1) ? w1 : w1n;
            const float* B = (mat == 0) ? b0 : (mat == 1) ? b1 : b1n;
            wtab[gid] = (c < 3) ? W[r*3 + c] : B[r];
        } else wtab[gid] = 0.f;
    }

    __syncthreads();

    int s = gid >> 5;
    if (s >= S) return;
    int k = gid & 31;

    float cr[9];
    #pragma unroll
    for (int j = 0; j < 9; j++) cr[j] = cell[s*9 + j];

    if (k == 0) {
        float a=cr[0],b=cr[1],c=cr[2],d=cr[3],e=cr[4],f=cr[5],g=cr[6],h=cr[7],i=cr[8];
        float A = e*i - f*h;
        float B = f*g - d*i;
        float C = d*h - e*g;
        float det = a*A + b*B + c*C;
        float r = 1.0f / det;
        float* o = ci_out + s*12;
        o[0] = A*r;         o[1] = (c*h - b*i)*r; o[2] = (b*f - c*e)*r;
        o[3] = B*r;         o[4] = (a*i - c*g)*r; o[5] = (c*d - a*f)*r;
        o[6] = C*r;         o[7] = (b*g - a*h)*r; o[8] = (a*e - b*d)*r;
        o[9] = 0.f; o[10] = 0.f; o[11] = 0.f;
    }

    float acc = b2a[k];
    const float* wr = sw + k*90 + 9;     // LDS
    #pragma unroll
    for (int j1 = 0; j1 < 9; j1++) {
        float c1 = cr[j1];
        #pragma unroll
        for (int j2 = 0; j2 < 9; j2++)
            acc = fmaf(c1 * cr[j2], wr[j1*9 + j2], acc);
    }
    cc_out[s*32 + k] = acc;
}

// ---------------- Kernel B: per-atom MLP + segment sum ---------------------
// R8 body (CHUNK=2, SMEM weights, shufflevector splats, 2-deep cc pipeline,
// direct-atomic tails) with w2bT moved to LDS: the two broadcast-weight
// streams now ride different pipes (SMEM scalar + DS) and overlap.
__global__ __launch_bounds__(BLOCK)
void main_kernel(const float* __restrict__ atom_prop,
                 const float* __restrict__ pos,
                 const int*   __restrict__ batch,
                 const float* __restrict__ ci_ws,
                 const float* __restrict__ cc_ws,
                 const float* __restrict__ wtab,
                 float* __restrict__ out,
                 int N, int S, int ntiles)
{
    __shared__ float ldsw[512];         // w2bT [32][16]
    int tid = threadIdx.x;
    int tile = blockIdx.x;

    // stage w2bT: 128 threads x one float4 = 512 floats, coalesced
    ((float4*)ldsw)[tid] = ((const float4*)(wtab + L_W2BT))[tid];

    // AS4 view of the weight table (cast via integer to sidestep
    // addrspace-conversion rules; the memory is written only by prep_kernel).
    cf* wt = (cf*)(unsigned long long)wtab;

    long long blk_base = (long long)tile * (BLOCK * CHUNK);
    long long base = blk_base + (long long)tid * CHUNK;
    bool any = (base < N);

    int   sv[CHUNK];
    float PX[CHUNK], PY[CHUNK], PZ[CHUNK];
    float AX[CHUNK], AY[CHUNK], AZ[CHUNK];

    if (any && base + CHUNK <= N) {
        int2 bb = *(const int2*)(batch + base);
        sv[0] = bb.x; sv[1] = bb.y;
        const float2* pp = (const float2*)(pos + 3*base);
        float2 p0 = pp[0], p1 = pp[1], p2 = pp[2];
        PX[0]=p0.x; PY[0]=p0.y; PZ[0]=p1.x;
        PX[1]=p1.y; PY[1]=p2.x; PZ[1]=p2.y;
        const float2* ap = (const float2*)(atom_prop + 3*base);
        float2 a0 = ap[0], a1 = ap[1], a2 = ap[2];
        AX[0]=a0.x; AY[0]=a0.y; AZ[0]=a1.x;
        AX[1]=a1.y; AY[1]=a2.x; AZ[1]=a2.y;
    } else {
        #pragma unroll
        for (int t = 0; t < CHUNK; t++) {
            long long i = base + t;
            bool ok = any && (i < N);
            sv[t] = ok ? batch[i] : -1;
            PX[t] = ok ? pos[3*i]   : 0.f;
            PY[t] = ok ? pos[3*i+1] : 0.f;
            PZ[t] = ok ? pos[3*i+2] : 0.f;
            AX[t] = ok ? atom_prop[3*i]   : 0.f;
            AY[t] = ok ? atom_prop[3*i+1] : 0.f;
            AZ[t] = ok ? atom_prop[3*i+2] : 0.f;
        }
    }

    // issue cc prefetch early, 2 blocks deep (covers ~2x L2 latency in kb loop)
    const float* ccp[CHUNK];
    #pragma unroll
    for (int t = 0; t < CHUNK; t++) {
        int s = sv[t] < 0 ? 0 : sv[t];
        ccp[t] = cc_ws + (size_t)s*32;
    }
    f4 c4n[CHUNK], c4nn[CHUNK];
    #pragma unroll
    for (int t = 0; t < CHUNK; t++) c4n[t]  = *(const f4*)(ccp[t]);
    #pragma unroll
    for (int t = 0; t < CHUNK; t++) c4nn[t] = *(const f4*)(ccp[t] + 4);

    // ---- phase 1: h per atom (splat pairs); w0/w1/w1n rows via s_load ----
    v2f h2[CHUNK][9];
    {
        cf4* q0 = (cf4*)(wt + L_W013);
        cf4* q1 = (cf4*)(wt + L_W013 + 12);
        cf4* q2 = (cf4*)(wt + L_W013 + 24);
        int   cur_s = -1;
        float ci[9];
        #pragma unroll
        for (int t = 0; t < CHUNK; t++) {
            int s = sv[t];
            if (s < 0) {
                #pragma unroll
                for (int j = 0; j < 9; j++) h2[t][j] = 0.f;
                continue;
            }
            if (s != cur_s) {
                cur_s = s;
                const f4* cip = (const f4*)(ci_ws + (size_t)s*12);
                f4 c0 = cip[0], c1 = cip[1], c2 = cip[2];
                ci[0]=c0.x; ci[1]=c0.y; ci[2]=c0.z; ci[3]=c0.w;
                ci[4]=c1.x; ci[5]=c1.y; ci[6]=c1.z; ci[7]=c1.w;
                ci[8]=c2.x;
            }
            float px = PX[t], py = PY[t], pz = PZ[t];
            float ax = AX[t], ay = AY[t], az = AZ[t];

            float f0 = fmaf(px, ci[0], fmaf(py, ci[3], pz*ci[6]));
            float f1 = fmaf(px, ci[1], fmaf(py, ci[4], pz*ci[7]));
            float f2 = fmaf(px, ci[2], fmaf(py, ci[5], pz*ci[8]));
            float t0 = f0 - floorf(f0) - 0.5f;
            float t1 = f1 - floorf(f1) - 0.5f;
            float t2 = f2 - floorf(f2) - 0.5f;

            h2[t][0].x = h2[t][0].y = ax;
            h2[t][1].x = h2[t][1].y = ay;
            h2[t][2].x = h2[t][2].y = az;
            #pragma unroll
            for (int r = 0; r < 3; r++) {
                f4 a0 = q0[r], a1 = q1[r], a2 = q2[r];
                float ap3 = leaky_(fmaf(ax, a0.x, fmaf(ay, a0.y, fmaf(az, a0.z, a0.w))));
                float d1  = fmaf(t0, a1.x, fmaf(t1, a1.y, fmaf(t2, a1.z, a1.w)));
                float d2  = a2.w - fmaf(t0, a2.x, fmaf(t1, a2.y, t2*a2.z));
                float v1 = fmaxf(d1, 0.f) * ap3;
                float v2 = fmaxf(d2, 0.f) * ap3;
                h2[t][3+r].x = h2[t][3+r].y = v1;
                h2[t][6+r].x = h2[t][6+r].y = v2;
            }
        }
    }

    __syncthreads();   // w2bT staged (placed late: staging latency hidden under phase 1)

    // ---- phase 2: fused L1+relu+L2; k-pair packed; wI via SMEM s_load,
    //      wb via LDS ds_read_b128 (two pipes overlap); cc 2-deep pipeline ----
    v2f vv[CHUNK][8];
    {
        cv2f* b2b2 = (cv2f*)(wt + L_B2B);
        #pragma unroll
        for (int t = 0; t < CHUNK; t++)
            #pragma unroll
            for (int m2 = 0; m2 < 8; m2++) vv[t][m2] = b2b2[m2];
    }

    #pragma unroll
    for (int kb = 0; kb < 8; kb++) {
        f4 c4[CHUNK];
        #pragma unroll
        for (int t = 0; t < CHUNK; t++) c4[t] = c4n[t];
        #pragma unroll
        for (int t = 0; t < CHUNK; t++) c4n[t] = c4nn[t];
        if (kb < 6) {
            #pragma unroll
            for (int t = 0; t < CHUNK; t++) c4nn[t] = *(const f4*)(ccp[t] + (kb+2)*4);
        }

        #pragma unroll
        for (int h = 0; h < 2; h++) {
            int kp = 2*kb + h;
            cv2f* wI = (cv2f*)(wt + L_W2AI + kp*20);       // uniform -> s_load pairs
            const v2f* wb0 = (const v2f*)(ldsw + (2*kp)*16);     // LDS b128 broadcast
            const v2f* wb1 = (const v2f*)(ldsw + (2*kp+1)*16);
            #pragma unroll
            for (int t = 0; t < CHUNK; t++) {
                v2f u2;
                u2.x = h ? c4[t].z : c4[t].x;
                u2.y = h ? c4[t].w : c4[t].y;
                #pragma unroll
                for (int j = 0; j < 9; j++) u2 = pk_fma(h2[t][j], wI[j], u2);
                v2f zero = 0.f;
                u2 = __builtin_elementwise_max(u2, zero);
                v2f ux = __builtin_shufflevector(u2, u2, 0, 0);
                v2f uy = __builtin_shufflevector(u2, u2, 1, 1);
                #pragma unroll
                for (int m2 = 0; m2 < 8; m2++) {
                    vv[t][m2] = pk_fma(ux, wb0[m2], vv[t][m2]);
                    vv[t][m2] = pk_fma(uy, wb1[m2], vv[t][m2]);
                }
            }
        }
    }

    // ---- epilogue: leaky, L3 (16->6) ----
    {
        v2f zero = 0.f, small = 0.01f;
        #pragma unroll
        for (int t = 0; t < CHUNK; t++)
            #pragma unroll
            for (int m2 = 0; m2 < 8; m2++) {
                v2f mx = __builtin_elementwise_max(vv[t][m2], zero);
                v2f mn = __builtin_elementwise_min(vv[t][m2], zero);
                vv[t][m2] = pk_fma(mn, small, mx);
            }
    }

    v2f oo[CHUNK][3];
    {
        cv2f* b2c2 = (cv2f*)(wt + L_B2C);
        #pragma unroll
        for (int t = 0; t < CHUNK; t++)
            #pragma unroll
            for (int p2 = 0; p2 < 3; p2++) oo[t][p2] = b2c2[p2];
    }
    #pragma unroll
    for (int m2 = 0; m2 < 8; m2++) {
        cv2f* wc0 = (cv2f*)(wt + L_W2CT + (2*m2)*8);   // uniform
        cv2f* wc1 = (cv2f*)(wt + L_W2CT + (2*m2+1)*8);
        #pragma unroll
        for (int t = 0; t < CHUNK; t++) {
            v2f vm = vv[t][m2];
            v2f a = __builtin_shufflevector(vm, vm, 0, 0);
            v2f b = __builtin_shufflevector(vm, vm, 1, 1);
            #pragma unroll
            for (int p2 = 0; p2 < 3; p2++)
                oo[t][p2] = pk_fma(a, wc0[p2], pk_fma(b, wc1[p2], oo[t][p2]));
        }
    }

    // ---- per-lane final (key, value); boundary tail -> direct global ----
    const int SENT = INT_MAX;
    int fs;
    float fin[6];
    {
        int sA = sv[0], sB = sv[1];
        if (sA < 0) {
            fs = SENT;
            #pragma unroll
            for (int p = 0; p < 6; p++) fin[p] = 0.f;
        } else if (sB == sA) {
            fs = sA;
            fin[0] = oo[0][0].x + oo[1][0].x; fin[1] = oo[0][0].y + oo[1][0].y;
            fin[2] = oo[0][1].x + oo[1][1].x; fin[3] = oo[0][1].y + oo[1][1].y;
            fin[4] = oo[0][2].x + oo[1][2].x; fin[5] = oo[0][2].y + oo[1][2].y;
        } else {
            float v0[6] = {oo[0][0].x, oo[0][0].y, oo[0][1].x, oo[0][1].y, oo[0][2].x, oo[0][2].y};
            #pragma unroll
            for (int p = 0; p < 6; p++) atomicAdd(out + (size_t)sA*6 + p, v0[p]);
            if (sB >= 0) {
                fs = sB;
                fin[0] = oo[1][0].x; fin[1] = oo[1][0].y;
                fin[2] = oo[1][1].x; fin[3] = oo[1][1].y;
                fin[4] = oo[1][2].x; fin[5] = oo[1][2].y;
            } else {
                fs = SENT;
                #pragma unroll
                for (int p = 0; p < 6; p++) fin[p] = 0.f;
            }
        }
    }

    // ---- segmented inclusive scan across the wave (keys sorted) ----
    int lane = tid & 63;
    #pragma unroll
    for (int d = 1; d < 64; d <<= 1) {
        int ks = __shfl_up(fs, d);
        bool pred = (lane >= d) && (ks == fs);
        #pragma unroll
        for (int p = 0; p < 6; p++) {
            float vp = __shfl_up(fin[p], d);
            fin[p] += pred ? vp : 0.f;
        }
    }
    {
        int sn = __shfl_down(fs, 1);
        bool tail = (lane == 63) || (sn != fs);
        if (tail && fs != SENT) {
            #pragma unroll
            for (int p = 0; p < 6; p++) atomicAdd(out + (size_t)fs*6 + p, fin[p]);
        }
    }
}

extern "C" void kernel_launch(void* const* d_in, const int* in_sizes, int n_in,
                              void* d_out, int out_size, void* d_ws, size_t ws_size,
                              hipStream_t stream)
{
    const float* atom_prop = (const float*)d_in[0];
    const float* pos       = (const float*)d_in[1];
    const float* cell      = (const float*)d_in[2];
    const int*   batch     = (const int*)  d_in[3];
    const float* w0  = (const float*)d_in[4];
    const float* b0  = (const float*)d_in[5];
    const float* w1  = (const float*)d_in[6];
    const float* b1  = (const float*)d_in[7];
    const float* w1n = (const float*)d_in[8];
    const float* b1n = (const float*)d_in[9];
    const float* w2a = (const float*)d_in[10];
    const float* b2a = (const float*)d_in[11];
    const float* w2b = (const float*)d_in[12];
    const float* b2b = (const float*)d_in[13];
    const float* w2c = (const float*)d_in[14];
    const float* b2c = (const float*)d_in[15];

    int N = in_sizes[3];          // batch has one entry per atom
    int S = in_sizes[2] / 9;      // cell is [S,3,3]

    float* out   = (float*)d_out;
    float* ci_ws = (float*)d_ws;                 // [S*12]
    float* cc_ws = ci_ws + (size_t)S*12;         // [S*32]
    float* wtab  = cc_ws + (size_t)S*32;         // [1024]

    int prep_threads = S * 32;
    prep_kernel<<<(prep_threads + 255)/256, 256, 0, stream>>>(
        cell, w2a, b2a, w2b, w2c, w0, b0, w1, b1, w1n, b1n, b2b, b2c,
        ci_ws, cc_ws, wtab, out, S);

    int tile_atoms = BLOCK * CHUNK;
    int ntiles = (N + tile_atoms - 1) / tile_atoms;
    main_kernel<<<ntiles, BLOCK, 0, stream>>>(atom_prop, pos, batch,
                                              ci_ws, cc_ws, wtab, out, N, S, ntiles);
}

// Round 11
// 162.400 us; speedup vs baseline: 1.9739x; 1.0137x over previous
//
#include <hip/hip_runtime.h>
#include <limits.h>

#define BLOCK 128
#define CHUNK 2

typedef float v2f __attribute__((ext_vector_type(2)));
typedef float f4  __attribute__((ext_vector_type(4)));

// Constant-address-space weight access: uniform address + AS4 => s_load
// (SGPR broadcast, scalar cache). Weight-pipe config space fully mapped:
// all-SMEM 59.0us (R8) < SMEM+LDS hybrid 61.2 (R10) < all-LDS 71.5 (R0)
// < all-VMEM 230 (R2). CHUNK axis closed: 2 optimal (3,4 refuted).
// R11 = R8 + int32 index math (N < 2^31): removes the v_add_co/addc
// 64-bit chains from prologue + cc setup (~100 VALU/wave-tile).
#define AS4 __attribute__((address_space(4)))
typedef AS4 const float cf;
typedef AS4 const f4    cf4;
typedef AS4 const v2f   cv2f;

__device__ __forceinline__ v2f pk_fma(v2f a, v2f b, v2f c) {
    return __builtin_elementwise_fma(a, b, c);
}
__device__ __forceinline__ float leaky_(float x){ return x >= 0.f ? x : 0.01f*x; }

// Packed weight-table layout (floats) in GLOBAL memory, read via AS4:
#define L_W2AI   0      // 16*20: k-pair interleaved {w2a[2kp][j],w2a[2kp+1][j]} j<9, pad 2
#define L_W2BT   320    // 32*16: w2bT[k][m] = w2b[m*32+k]
#define L_W2CT   832    // 16*8 : w2cT[m][p] = w2c[p*16+m], pad p<8
#define L_B2B    960    // 16
#define L_B2C    976    // 8 (pad)
#define L_W013   984    // 3 mats x 3 rows x4: (w,w,w,b) for w0,w1,w1n
#define WTAB_SZ  1024

// ---------------- Kernel A: per-structure precompute + weight packing ------
__global__ void prep_kernel(const float* __restrict__ cell,
                            const float* __restrict__ w2a,
                            const float* __restrict__ b2a,
                            const float* __restrict__ w2b,
                            const float* __restrict__ w2c,
                            const float* __restrict__ w0, const float* __restrict__ b0,
                            const float* __restrict__ w1, const float* __restrict__ b1,
                            const float* __restrict__ w1n, const float* __restrict__ b1n,
                            const float* __restrict__ b2b, const float* __restrict__ b2c,
                            float* __restrict__ ci_out,
                            float* __restrict__ cc_out,
                            float* __restrict__ wtab,
                            float* __restrict__ out_zero,
                            int S)
{
    __shared__ float sw[2880];          // all of w2a [32][90]
    int tid = threadIdx.x;
    int gid = blockIdx.x * blockDim.x + tid;

    #pragma unroll
    for (int t = 0; t < 3; t++) {
        int idx = tid + t*256;
        if (idx < 720) ((float4*)sw)[idx] = ((const float4*)w2a)[idx];
    }

    if (gid < S * 6) out_zero[gid] = 0.f;

    // ---- wtab packing (few threads; scattered loads negligible) ----
    if (gid < 320) {
        int kp = gid / 20, idx = gid % 20;
        int j = idx >> 1, h = idx & 1;
        wtab[L_W2AI + gid] = (idx < 18) ? w2a[(2*kp + h)*90 + j] : 0.f;
    } else if (gid < 832) {
        int t = gid - 320; int k = t >> 4, m = t & 15;
        wtab[gid] = w2b[m*32 + k];
    } else if (gid < 960) {
        int t = gid - 832; int m = t >> 3, p = t & 7;
        wtab[gid] = (p < 6) ? w2c[p*16 + m] : 0.f;
    } else if (gid < 976) {
        wtab[gid] = b2b[gid - 960];
    } else if (gid < 984) {
        int t = gid - 976; wtab[gid] = (t < 6) ? b2c[t] : 0.f;
    } else if (gid < 1024) {
        int t = gid - 984;
        if (t < 36) {
            int mat = t / 12, rr = t % 12, r = rr >> 2, c = rr & 3;
            const float* W = (mat == 0) ? w0 : (mat == 1) ? w1 : w1n;
            const float* B = (mat == 0) ? b0 : (mat == 1) ? b1 : b1n;
            wtab[gid] = (c < 3) ? W[r*3 + c] : B[r];
        } else wtab[gid] = 0.f;
    }

    __syncthreads();

    int s = gid >> 5;
    if (s >= S) return;
    int k = gid & 31;

    float cr[9];
    #pragma unroll
    for (int j = 0; j < 9; j++) cr[j] = cell[s*9 + j];

    if (k == 0) {
        float a=cr[0],b=cr[1],c=cr[2],d=cr[3],e=cr[4],f=cr[5],g=cr[6],h=cr[7],i=cr[8];
        float A = e*i - f*h;
        float B = f*g - d*i;
        float C = d*h - e*g;
        float det = a*A + b*B + c*C;
        float r = 1.0f / det;
        float* o = ci_out + s*12;
        o[0] = A*r;         o[1] = (c*h - b*i)*r; o[2] = (b*f - c*e)*r;
        o[3] = B*r;         o[4] = (a*i - c*g)*r; o[5] = (c*d - a*f)*r;
        o[6] = C*r;         o[7] = (b*g - a*h)*r; o[8] = (a*e - b*d)*r;
        o[9] = 0.f; o[10] = 0.f; o[11] = 0.f;
    }

    float acc = b2a[k];
    const float* wr = sw + k*90 + 9;     // LDS
    #pragma unroll
    for (int j1 = 0; j1 < 9; j1++) {
        float c1 = cr[j1];
        #pragma unroll
        for (int j2 = 0; j2 < 9; j2++)
            acc = fmaf(c1 * cr[j2], wr[j1*9 + j2], acc);
    }
    cc_out[s*32 + k] = acc;
}

// ---------------- Kernel B: per-atom MLP + segment sum ---------------------
// R8 body (CHUNK=2, SMEM weights, shufflevector splats, 2-deep cc pipeline,
// no LDS, no barriers, direct-atomic tails) with int32 index arithmetic.
__global__ __launch_bounds__(BLOCK)
void main_kernel(const float* __restrict__ atom_prop,
                 const float* __restrict__ pos,
                 const int*   __restrict__ batch,
                 const float* __restrict__ ci_ws,
                 const float* __restrict__ cc_ws,
                 const float* __restrict__ wtab,
                 float* __restrict__ out,
                 int N, int S, int ntiles)
{
    int tid = threadIdx.x;
    int tile = blockIdx.x;
    if (tile >= ntiles) return;

    // AS4 view of the weight table (cast via integer to sidestep
    // addrspace-conversion rules; the memory is written only by prep_kernel).
    cf* wt = (cf*)(unsigned long long)wtab;

    // int32 index math throughout: N < 2^31 and ntiles*BLOCK*CHUNK < 2^31,
    // so all element indices fit int; the compiler emits one lshl_add_u64
    // per final address instead of 64-bit add chains.
    int base = tile * (BLOCK * CHUNK) + tid * CHUNK;
    bool any = (base < N);

    int   sv[CHUNK];
    float PX[CHUNK], PY[CHUNK], PZ[CHUNK];
    float AX[CHUNK], AY[CHUNK], AZ[CHUNK];

    if (any && base + CHUNK <= N) {
        int2 bb = *(const int2*)(batch + base);
        sv[0] = bb.x; sv[1] = bb.y;
        const float2* pp = (const float2*)(pos + 3*base);
        float2 p0 = pp[0], p1 = pp[1], p2 = pp[2];
        PX[0]=p0.x; PY[0]=p0.y; PZ[0]=p1.x;
        PX[1]=p1.y; PY[1]=p2.x; PZ[1]=p2.y;
        const float2* ap = (const float2*)(atom_prop + 3*base);
        float2 a0 = ap[0], a1 = ap[1], a2 = ap[2];
        AX[0]=a0.x; AY[0]=a0.y; AZ[0]=a1.x;
        AX[1]=a1.y; AY[1]=a2.x; AZ[1]=a2.y;
    } else {
        #pragma unroll
        for (int t = 0; t < CHUNK; t++) {
            int i = base + t;
            bool ok = any && (i < N);
            sv[t] = ok ? batch[i] : -1;
            PX[t] = ok ? pos[3*i]   : 0.f;
            PY[t] = ok ? pos[3*i+1] : 0.f;
            PZ[t] = ok ? pos[3*i+2] : 0.f;
            AX[t] = ok ? atom_prop[3*i]   : 0.f;
            AY[t] = ok ? atom_prop[3*i+1] : 0.f;
            AZ[t] = ok ? atom_prop[3*i+2] : 0.f;
        }
    }

    // issue cc prefetch early, 2 blocks deep (covers ~2x L2 latency in kb loop)
    const float* ccp[CHUNK];
    #pragma unroll
    for (int t = 0; t < CHUNK; t++) {
        int s = sv[t] < 0 ? 0 : sv[t];
        ccp[t] = cc_ws + (unsigned)(s*32);
    }
    f4 c4n[CHUNK], c4nn[CHUNK];
    #pragma unroll
    for (int t = 0; t < CHUNK; t++) c4n[t]  = *(const f4*)(ccp[t]);
    #pragma unroll
    for (int t = 0; t < CHUNK; t++) c4nn[t] = *(const f4*)(ccp[t] + 4);

    // ---- phase 1: h per atom (splat pairs); w0/w1/w1n rows via s_load ----
    v2f h2[CHUNK][9];
    {
        cf4* q0 = (cf4*)(wt + L_W013);
        cf4* q1 = (cf4*)(wt + L_W013 + 12);
        cf4* q2 = (cf4*)(wt + L_W013 + 24);
        int   cur_s = -1;
        float ci[9];
        #pragma unroll
        for (int t = 0; t < CHUNK; t++) {
            int s = sv[t];
            if (s < 0) {
                #pragma unroll
                for (int j = 0; j < 9; j++) h2[t][j] = 0.f;
                continue;
            }
            if (s != cur_s) {
                cur_s = s;
                const f4* cip = (const f4*)(ci_ws + (unsigned)(s*12));
                f4 c0 = cip[0], c1 = cip[1], c2 = cip[2];
                ci[0]=c0.x; ci[1]=c0.y; ci[2]=c0.z; ci[3]=c0.w;
                ci[4]=c1.x; ci[5]=c1.y; ci[6]=c1.z; ci[7]=c1.w;
                ci[8]=c2.x;
            }
            float px = PX[t], py = PY[t], pz = PZ[t];
            float ax = AX[t], ay = AY[t], az = AZ[t];

            float f0 = fmaf(px, ci[0], fmaf(py, ci[3], pz*ci[6]));
            float f1 = fmaf(px, ci[1], fmaf(py, ci[4], pz*ci[7]));
            float f2 = fmaf(px, ci[2], fmaf(py, ci[5], pz*ci[8]));
            float t0 = f0 - floorf(f0) - 0.5f;
            float t1 = f1 - floorf(f1) - 0.5f;
            float t2 = f2 - floorf(f2) - 0.5f;

            h2[t][0].x = h2[t][0].y = ax;
            h2[t][1].x = h2[t][1].y = ay;
            h2[t][2].x = h2[t][2].y = az;
            #pragma unroll
            for (int r = 0; r < 3; r++) {
                f4 a0 = q0[r], a1 = q1[r], a2 = q2[r];
                float ap3 = leaky_(fmaf(ax, a0.x, fmaf(ay, a0.y, fmaf(az, a0.z, a0.w))));
                float d1  = fmaf(t0, a1.x, fmaf(t1, a1.y, fmaf(t2, a1.z, a1.w)));
                float d2  = a2.w - fmaf(t0, a2.x, fmaf(t1, a2.y, t2*a2.z));
                float v1 = fmaxf(d1, 0.f) * ap3;
                float v2 = fmaxf(d2, 0.f) * ap3;
                h2[t][3+r].x = h2[t][3+r].y = v1;
                h2[t][6+r].x = h2[t][6+r].y = v2;
            }
        }
    }

    // ---- phase 2: fused L1+relu+L2; k-pair packed; SMEM weights;
    //      cc loads software-pipelined 2 blocks deep ----
    v2f vv[CHUNK][8];
    {
        cv2f* b2b2 = (cv2f*)(wt + L_B2B);
        #pragma unroll
        for (int t = 0; t < CHUNK; t++)
            #pragma unroll
            for (int m2 = 0; m2 < 8; m2++) vv[t][m2] = b2b2[m2];
    }

    #pragma unroll
    for (int kb = 0; kb < 8; kb++) {
        f4 c4[CHUNK];
        #pragma unroll
        for (int t = 0; t < CHUNK; t++) c4[t] = c4n[t];
        #pragma unroll
        for (int t = 0; t < CHUNK; t++) c4n[t] = c4nn[t];
        if (kb < 6) {
            #pragma unroll
            for (int t = 0; t < CHUNK; t++) c4nn[t] = *(const f4*)(ccp[t] + (kb+2)*4);
        }

        #pragma unroll
        for (int h = 0; h < 2; h++) {
            int kp = 2*kb + h;
            cv2f* wI  = (cv2f*)(wt + L_W2AI + kp*20);       // uniform -> s_load pairs
            cv2f* wb0 = (cv2f*)(wt + L_W2BT + (2*kp)*16);
            cv2f* wb1 = (cv2f*)(wt + L_W2BT + (2*kp+1)*16);
            #pragma unroll
            for (int t = 0; t < CHUNK; t++) {
                v2f u2;
                u2.x = h ? c4[t].z : c4[t].x;
                u2.y = h ? c4[t].w : c4[t].y;
                #pragma unroll
                for (int j = 0; j < 9; j++) u2 = pk_fma(h2[t][j], wI[j], u2);
                v2f zero = 0.f;
                u2 = __builtin_elementwise_max(u2, zero);
                v2f ux = __builtin_shufflevector(u2, u2, 0, 0);
                v2f uy = __builtin_shufflevector(u2, u2, 1, 1);
                #pragma unroll
                for (int m2 = 0; m2 < 8; m2++) {
                    vv[t][m2] = pk_fma(ux, wb0[m2], vv[t][m2]);
                    vv[t][m2] = pk_fma(uy, wb1[m2], vv[t][m2]);
                }
            }
        }
    }

    // ---- epilogue: leaky, L3 (16->6) ----
    {
        v2f zero = 0.f, small = 0.01f;
        #pragma unroll
        for (int t = 0; t < CHUNK; t++)
            #pragma unroll
            for (int m2 = 0; m2 < 8; m2++) {
                v2f mx = __builtin_elementwise_max(vv[t][m2], zero);
                v2f mn = __builtin_elementwise_min(vv[t][m2], zero);
                vv[t][m2] = pk_fma(mn, small, mx);
            }
    }

    v2f oo[CHUNK][3];
    {
        cv2f* b2c2 = (cv2f*)(wt + L_B2C);
        #pragma unroll
        for (int t = 0; t < CHUNK; t++)
            #pragma unroll
            for (int p2 = 0; p2 < 3; p2++) oo[t][p2] = b2c2[p2];
    }
    #pragma unroll
    for (int m2 = 0; m2 < 8; m2++) {
        cv2f* wc0 = (cv2f*)(wt + L_W2CT + (2*m2)*8);   // uniform
        cv2f* wc1 = (cv2f*)(wt + L_W2CT + (2*m2+1)*8);
        #pragma unroll
        for (int t = 0; t < CHUNK; t++) {
            v2f vm = vv[t][m2];
            v2f a = __builtin_shufflevector(vm, vm, 0, 0);
            v2f b = __builtin_shufflevector(vm, vm, 1, 1);
            #pragma unroll
            for (int p2 = 0; p2 < 3; p2++)
                oo[t][p2] = pk_fma(a, wc0[p2], pk_fma(b, wc1[p2], oo[t][p2]));
        }
    }

    // ---- per-lane final (key, value); boundary tail -> direct global ----
    const int SENT = INT_MAX;
    int fs;
    float fin[6];
    {
        int sA = sv[0], sB = sv[1];
        if (sA < 0) {
            fs = SENT;
            #pragma unroll
            for (int p = 0; p < 6; p++) fin[p] = 0.f;
        } else if (sB == sA) {
            fs = sA;
            fin[0] = oo[0][0].x + oo[1][0].x; fin[1] = oo[0][0].y + oo[1][0].y;
            fin[2] = oo[0][1].x + oo[1][1].x; fin[3] = oo[0][1].y + oo[1][1].y;
            fin[4] = oo[0][2].x + oo[1][2].x; fin[5] = oo[0][2].y + oo[1][2].y;
        } else {
            float v0[6] = {oo[0][0].x, oo[0][0].y, oo[0][1].x, oo[0][1].y, oo[0][2].x, oo[0][2].y};
            float* oa = out + (unsigned)(sA*6);
            #pragma unroll
            for (int p = 0; p < 6; p++) atomicAdd(oa + p, v0[p]);
            if (sB >= 0) {
                fs = sB;
                fin[0] = oo[1][0].x; fin[1] = oo[1][0].y;
                fin[2] = oo[1][1].x; fin[3] = oo[1][1].y;
                fin[4] = oo[1][2].x; fin[5] = oo[1][2].y;
            } else {
                fs = SENT;
                #pragma unroll
                for (int p = 0; p < 6; p++) fin[p] = 0.f;
            }
        }
    }

    // ---- segmented inclusive scan across the wave (keys sorted) ----
    int lane = tid & 63;
    #pragma unroll
    for (int d = 1; d < 64; d <<= 1) {
        int ks = __shfl_up(fs, d);
        bool pred = (lane >= d) && (ks == fs);
        #pragma unroll
        for (int p = 0; p < 6; p++) {
            float vp = __shfl_up(fin[p], d);
            fin[p] += pred ? vp : 0.f;
        }
    }
    {
        int sn = __shfl_down(fs, 1);
        bool tail = (lane == 63) || (sn != fs);
        if (tail && fs != SENT) {
            float* ob = out + (unsigned)(fs*6);
            #pragma unroll
            for (int p = 0; p < 6; p++) atomicAdd(ob + p, fin[p]);
        }
    }
}

extern "C" void kernel_launch(void* const* d_in, const int* in_sizes, int n_in,
                              void* d_out, int out_size, void* d_ws, size_t ws_size,
                              hipStream_t stream)
{
    const float* atom_prop = (const float*)d_in[0];
    const float* pos       = (const float*)d_in[1];
    const float* cell      = (const float*)d_in[2];
    const int*   batch     = (const int*)  d_in[3];
    const float* w0  = (const float*)d_in[4];
    const float* b0  = (const float*)d_in[5];
    const float* w1  = (const float*)d_in[6];
    const float* b1  = (const float*)d_in[7];
    const float* w1n = (const float*)d_in[8];
    const float* b1n = (const float*)d_in[9];
    const float* w2a = (const float*)d_in[10];
    const float* b2a = (const float*)d_in[11];
    const float* w2b = (const float*)d_in[12];
    const float* b2b = (const float*)d_in[13];
    const float* w2c = (const float*)d_in[14];
    const float* b2c = (const float*)d_in[15];

    int N = in_sizes[3];          // batch has one entry per atom
    int S = in_sizes[2] / 9;      // cell is [S,3,3]

    float* out   = (float*)d_out;
    float* ci_ws = (float*)d_ws;                 // [S*12]
    float* cc_ws = ci_ws + (size_t)S*12;         // [S*32]
    float* wtab  = cc_ws + (size_t)S*32;         // [1024]

    int prep_threads = S * 32;
    prep_kernel<<<(prep_threads + 255)/256, 256, 0, stream>>>(
        cell, w2a, b2a, w2b, w2c, w0, b0, w1, b1, w1n, b1n, b2b, b2c,
        ci_ws, cc_ws, wtab, out, S);

    int tile_atoms = BLOCK * CHUNK;
    int ntiles = (N + tile_atoms - 1) / tile_atoms;
    main_kernel<<<ntiles, BLOCK, 0, stream>>>(atom_prop, pos, batch,
                                              ci_ws, cc_ws, wtab, out, N, S, ntiles);
}